// Round 8
// baseline (233.987 us; speedup 1.0000x reference)
//
#include <hip/hip_runtime.h>

namespace {

constexpr int kB = 256;
constexpr int kT = 1024;
constexpr int kC = 64;
constexpr int kHalfT = 512;
constexpr int kGroups = 64;   // 64 groups * 8 steps = 512 steps per direction

typedef _Float16 half1_t;
typedef _Float16 half2_t __attribute__((ext_vector_type(2)));

#if __has_builtin(__builtin_amdgcn_fdot2)
#define HAVE_FDOT2 1
#else
#define HAVE_FDOT2 0
#endif

__device__ __forceinline__ float dot2f(half2_t a, half2_t b, float c) {
#if HAVE_FDOT2
  return __builtin_amdgcn_fdot2(a, b, c, false);
#else
  return c + (float)a.x * (float)b.x + (float)a.y * (float)b.y;
#endif
}

__device__ __forceinline__ half2_t as_h2(unsigned int u) {
  return __builtin_bit_cast(half2_t, u);
}

// workspace float layout:
//   [0      .. 16383]  u[b][j]  : fwd scaled alpha_{511}
//   [16384  .. 32767]  v[b][j]  : bwd scaled beta-vector at the split
//   [32768  .. 34815]  meta[b][8]: 0=sacc_f 1=sx_f 2=pe_f  4=sacc_b 5=sx_b 6=pe_b

// 512 blocks x 1 wave. blocks [0,256): forward half; [256,512): backward half.
// lane = class. Linear-domain recursion, f16 state in LDS, f16 W in regs.
// Numeric control:
//   - group bias gm = wave-max over the group's 8 x-vectors -> Fp=exp(x-gm)<=1
//   - pow2 renorm, DELAY-1 dead-beat: d1 = exponent of wave-max(pl_{s-1}),
//     applied at step s (folded into F). e_s = c_s: unconditionally stable.
//     Stored f16 <= 64*2*e^0.5 ~ 211 << 65504. The butterfly max runs in
//     parallel with the LDS round-trip (both depend only on pl_{s-1}).
__global__ __launch_bounds__(64, 1) void crf_half(
    const float* __restrict__ x,    // [B,T,C]
    const float* __restrict__ U,    // [C,C]
    const float* __restrict__ bs,   // [C]
    const float* __restrict__ be,   // [C]
    const int*   __restrict__ y,    // [B,T]
    float*       __restrict__ wsf)
{
  const int blk = blockIdx.x;
  const int dir = blk >> 8;      // 0 = forward, 1 = backward
  const int b   = blk & 255;
  const int j   = threadIdx.x & 63;

  __shared__ __align__(16) half1_t pbuf[kC];

  const float* xbase = x + (size_t)b * kT * kC;
  const float* xcol  = xbase + j;
  const int*   yrow  = y + (size_t)b * kT;

  // ---- half path-energy prepass: 8 timesteps per lane ----
  float pe = 0.f;
  {
    const int t0 = (dir ? kHalfT : 0) + j * 8;
    int yv[9];
#pragma unroll
    for (int k = 0; k < 8; ++k) yv[k + 1] = yrow[t0 + k];
    yv[0] = (t0 > 0) ? yrow[t0 - 1] : 0;
#pragma unroll
    for (int k = 0; k < 8; ++k) {
      const int t = t0 + k;
      pe += xbase[(size_t)t * kC + yv[k + 1]];          // emission
      if (t >= 1) pe += U[yv[k] * kC + yv[k + 1]];      // transition
    }
    if (dir == 0 && j == 0)  pe += bs[yv[1]];           // boundary y[0]
    if (dir == 1 && j == 63) pe += be[yv[8]];           // boundary y[T-1]
#pragma unroll
    for (int off = 32; off >= 1; off >>= 1) pe += __shfl_xor(pe, off, 64);
  }

  // ---- W fragment: fwd lane j = column j of exp(U); bwd lane j = row j ----
  half2_t Wp[32];
#pragma unroll
  for (int w = 0; w < 32; ++w) {
    float e0, e1;
    if (dir == 0) { e0 = U[(2 * w) * kC + j];  e1 = U[(2 * w + 1) * kC + j]; }
    else          { e0 = U[j * kC + 2 * w];    e1 = U[j * kC + 2 * w + 1];   }
    half2_t hw;
    hw.x = (half1_t)__expf(e0);
    hw.y = (half1_t)__expf(e1);
    Wp[w] = hw;
  }

  const float bnd = dir ? be[j] : bs[j];

  // time index for step s: fwd -> s, bwd -> T-1-s
  float xb[8];
#pragma unroll
  for (int k = 0; k < 8; ++k) {
    const int t = dir ? (kT - 1 - k) : k;
    xb[k] = xcol[t * kC];
  }
  xb[0] += bnd;   // s=0 boundary (fwd t=0 += bs, bwd t=1023 += be)

  float pl   = 1.f;   // bwd init state (fwd overwritten at s=0)
  float sx   = 0.f;   // uniform accumulated bias
  int   sacc = 0;     // uniform accumulated pow2 exponents (applied only)
  int   d1   = 0;     // exponent measured from previous step's pl

  for (int g = 0; g < kGroups; ++g) {
    float xn[8];
    const bool more = (g < kGroups - 1);
    if (more) {
#pragma unroll
      for (int k = 0; k < 8; ++k) {
        const int s = 8 * (g + 1) + k;
        const int t = dir ? (kT - 1 - s) : s;
        xn[k] = xcol[t * kC];
      }
    }

    // ---- group bias: wave-and-group max of x (off critical path) ----
    float gm = xb[0];
#pragma unroll
    for (int k = 1; k < 8; ++k) gm = fmaxf(gm, xb[k]);
#pragma unroll
    for (int off = 32; off >= 1; off >>= 1) gm = fmaxf(gm, __shfl_xor(gm, off, 64));
    float Fp[8];
#pragma unroll
    for (int k = 0; k < 8; ++k) Fp[k] = __expf(xb[k] - gm);
    sx += 8.f * gm;

#pragma unroll
    for (int k = 0; k < 8; ++k) {
      // delay-1 renorm: scale by 2^{-d1} (d1 from previous step's pl)
      const float scl = __uint_as_float((unsigned)(127 - d1) << 23);
      const float F = Fp[k] * scl;
      sacc += d1;

      if (dir == 0) {
        if (g == 0 && k == 0) {
          pl = F;                            // scaled alpha_0
        } else {
          const uint4* sh = reinterpret_cast<const uint4*>(pbuf);
          float acc[8];
#pragma unroll
          for (int q = 0; q < 8; ++q) {
            const uint4 vv = sh[q];
            float a;
            a = dot2f(as_h2(vv.x), Wp[4 * q + 0], 0.f);
            a = dot2f(as_h2(vv.y), Wp[4 * q + 1], a);
            a = dot2f(as_h2(vv.z), Wp[4 * q + 2], a);
            a = dot2f(as_h2(vv.w), Wp[4 * q + 3], a);
            acc[q] = a;
          }
          const float s01 = acc[0] + acc[1], s23 = acc[2] + acc[3];
          const float s45 = acc[4] + acc[5], s67 = acc[6] + acc[7];
          pl = ((s01 + s23) + (s45 + s67)) * F;
        }
        pbuf[j] = (half1_t)pl;
      } else {
        const float q16 = pl * F;            // q = beta * E (scaled)
        pbuf[j] = (half1_t)q16;
        const uint4* sh = reinterpret_cast<const uint4*>(pbuf);
        float acc[8];
#pragma unroll
        for (int q = 0; q < 8; ++q) {
          const uint4 vv = sh[q];
          float a;
          a = dot2f(as_h2(vv.x), Wp[4 * q + 0], 0.f);
          a = dot2f(as_h2(vv.y), Wp[4 * q + 1], a);
          a = dot2f(as_h2(vv.z), Wp[4 * q + 2], a);
          a = dot2f(as_h2(vv.w), Wp[4 * q + 3], a);
          acc[q] = a;
        }
        const float s01 = acc[0] + acc[1], s23 = acc[2] + acc[3];
        const float s45 = acc[4] + acc[5], s67 = acc[6] + acc[7];
        pl = (s01 + s23) + (s45 + s67);
      }

      // measure next step's renorm exponent: wave-max butterfly (parallel
      // with the next step's LDS round-trip; not on the serial chain)
      float m = pl;
#pragma unroll
      for (int off = 32; off >= 1; off >>= 1) m = fmaxf(m, __shfl_xor(m, off, 64));
      d1 = ((int)((__float_as_uint(m) >> 23) & 255)) - 127;
    }

    if (more) {
#pragma unroll
      for (int k = 0; k < 8; ++k) xb[k] = xn[k];
    }
  }

  // ---- write results (raw pl; only applied scales are in sacc/sx) ----
  float* meta = wsf + 32768 + (size_t)b * 8;
  if (dir == 0) {
    wsf[(size_t)b * kC + j] = pl;
    if (j == 0) {
      meta[0] = (float)sacc;
      meta[1] = sx;
      meta[2] = pe;
    }
  } else {
    wsf[16384 + (size_t)b * kC + j] = pl;
    if (j == 0) {
      meta[4] = (float)sacc;
      meta[5] = sx;
      meta[6] = pe;
    }
  }
}

// combine: Z = sum_j u[j]*v[j] (with accumulated scales), out = logZ - pathE
__global__ __launch_bounds__(64, 1) void crf_combine(
    const float* __restrict__ wsf, float* __restrict__ out)
{
  const int b = blockIdx.x;
  const int j = threadIdx.x & 63;

  const float u = wsf[(size_t)b * kC + j];
  const float v = wsf[16384 + (size_t)b * kC + j];
  float p = u * v;
#pragma unroll
  for (int off = 32; off >= 1; off >>= 1) p += __shfl_xor(p, off, 64);

  if (j == 0) {
    const float* meta = wsf + 32768 + (size_t)b * 8;
    const float logz = (meta[0] + meta[4]) * 0.69314718055994531f +
                       meta[1] + meta[5] + __logf(p);
    out[b] = logz - (meta[2] + meta[6]);
  }
}

}  // namespace

extern "C" void kernel_launch(void* const* d_in, const int* in_sizes, int n_in,
                              void* d_out, int out_size, void* d_ws, size_t ws_size,
                              hipStream_t stream) {
  const float* x  = (const float*)d_in[0];
  const float* U  = (const float*)d_in[1];
  const float* bs = (const float*)d_in[2];
  const float* be = (const float*)d_in[3];
  const int*   y  = (const int*)d_in[4];
  float* out = (float*)d_out;
  float* wsf = (float*)d_ws;

  crf_half<<<2 * kB, 64, 0, stream>>>(x, U, bs, be, y, wsf);
  crf_combine<<<kB, 64, 0, stream>>>(wsf, out);
}

// Round 9
// 137.988 us; speedup vs baseline: 1.6957x; 1.6957x over previous
//
#include <hip/hip_runtime.h>

namespace {

constexpr int kB = 256;
constexpr int kT = 1024;
constexpr int kC = 64;
constexpr int kHalfT = 512;
constexpr int kGroups = 64;   // 64 groups * 8 steps = 512 steps per direction

typedef _Float16 half1_t;
typedef _Float16 half2_t __attribute__((ext_vector_type(2)));

#if __has_builtin(__builtin_amdgcn_fdot2)
#define HAVE_FDOT2 1
#else
#define HAVE_FDOT2 0
#endif

__device__ __forceinline__ float dot2f(half2_t a, half2_t b, float c) {
#if HAVE_FDOT2
  return __builtin_amdgcn_fdot2(a, b, c, false);
#else
  return c + (float)a.x * (float)b.x + (float)a.y * (float)b.y;
#endif
}

__device__ __forceinline__ half2_t as_h2(unsigned int u) {
  return __builtin_bit_cast(half2_t, u);
}

// workspace float layout:
//   [0      .. 16383]  u[b][j]  : fwd scaled alpha_{511}
//   [16384  .. 32767]  v[b][j]  : bwd scaled beta-vector at the split
//   [32768  .. 34815]  meta[b][8]: 0=sacc_f 2=pe_f  4=sacc_b 6=pe_b

// 512 blocks x 1 wave. blocks [0,256): forward half; [256,512): backward half.
// lane = class. Linear-domain recursion, f16 state in LDS, f16 W in regs.
// Renorm: IMMEDIATE lane-0 exponent via readfirstlane (SALU — cheap; NO
// shuffle butterflies anywhere in the loop; CDNA shuffles are LDS-class ops,
// measured +600 cyc/step in round 8). Scale applied before the f16 store:
// stored lane0 ~ [1,2), others <= e^{log-spread ~8} ~ 3e3 << 65504.
// fwd renorms alpha; bwd renorms q = beta*E (after the E-multiply, so the
// x-spread never reaches the store unscaled). Proven stable mechanics
// (round 5, absmax 0.0 over 1024 steps).
__global__ __launch_bounds__(64, 1) void crf_half(
    const float* __restrict__ x,    // [B,T,C]
    const float* __restrict__ U,    // [C,C]
    const float* __restrict__ bs,   // [C]
    const float* __restrict__ be,   // [C]
    const int*   __restrict__ y,    // [B,T]
    float*       __restrict__ wsf)
{
  const int blk = blockIdx.x;
  const int dir = blk >> 8;      // 0 = forward, 1 = backward
  const int b   = blk & 255;
  const int j   = threadIdx.x & 63;

  __shared__ __align__(16) half1_t pbuf[kC];

  const float* xbase = x + (size_t)b * kT * kC;
  const float* xcol  = xbase + j;
  const int*   yrow  = y + (size_t)b * kT;

  // ---- half path-energy prepass: 8 timesteps per lane ----
  float pe = 0.f;
  {
    const int t0 = (dir ? kHalfT : 0) + j * 8;
    int yv[9];
#pragma unroll
    for (int k = 0; k < 8; ++k) yv[k + 1] = yrow[t0 + k];
    yv[0] = (t0 > 0) ? yrow[t0 - 1] : 0;
#pragma unroll
    for (int k = 0; k < 8; ++k) {
      const int t = t0 + k;
      pe += xbase[(size_t)t * kC + yv[k + 1]];          // emission
      if (t >= 1) pe += U[yv[k] * kC + yv[k + 1]];      // transition
    }
    if (dir == 0 && j == 0)  pe += bs[yv[1]];           // boundary y[0]
    if (dir == 1 && j == 63) pe += be[yv[8]];           // boundary y[T-1]
#pragma unroll
    for (int off = 32; off >= 1; off >>= 1) pe += __shfl_xor(pe, off, 64);
  }

  // ---- W fragment: fwd lane j = column j of exp(U); bwd lane j = row j ----
  half2_t Wp[32];
#pragma unroll
  for (int w = 0; w < 32; ++w) {
    float e0, e1;
    if (dir == 0) { e0 = U[(2 * w) * kC + j];  e1 = U[(2 * w + 1) * kC + j]; }
    else          { e0 = U[j * kC + 2 * w];    e1 = U[j * kC + 2 * w + 1];   }
    half2_t hw;
    hw.x = (half1_t)__expf(e0);
    hw.y = (half1_t)__expf(e1);
    Wp[w] = hw;
  }

  const float bnd = dir ? be[j] : bs[j];

  // time index for step s: fwd -> s, bwd -> T-1-s
  float xb[8];
#pragma unroll
  for (int k = 0; k < 8; ++k) {
    const int t = dir ? (kT - 1 - k) : k;
    xb[k] = xcol[t * kC];
  }
  xb[0] += bnd;   // s=0 boundary (fwd t=0 += bs, bwd t=1023 += be)

  float pl   = 1.f;   // bwd init state (fwd overwritten at s=0)
  int   sacc = 0;     // uniform accumulated pow2 exponents

  for (int g = 0; g < kGroups; ++g) {
    float xn[8];
    const bool more = (g < kGroups - 1);
    if (more) {
#pragma unroll
      for (int k = 0; k < 8; ++k) {
        const int s = 8 * (g + 1) + k;
        const int t = dir ? (kT - 1 - s) : s;
        xn[k] = xcol[t * kC];
      }
    }

    // E for this group — off the p critical path
    float Eb[8];
#pragma unroll
    for (int k = 0; k < 8; ++k) Eb[k] = __expf(xb[k]);

#pragma unroll
    for (int k = 0; k < 8; ++k) {
      if (dir == 0) {
        float pn;
        if (g == 0 && k == 0) {
          pn = Eb[0];                        // alpha_0 = exp(x0+bs)
        } else {
          const uint4* sh = reinterpret_cast<const uint4*>(pbuf);
          float acc[8];
#pragma unroll
          for (int q = 0; q < 8; ++q) {
            const uint4 vv = sh[q];
            float a;
            a = dot2f(as_h2(vv.x), Wp[4 * q + 0], 0.f);
            a = dot2f(as_h2(vv.y), Wp[4 * q + 1], a);
            a = dot2f(as_h2(vv.z), Wp[4 * q + 2], a);
            a = dot2f(as_h2(vv.w), Wp[4 * q + 3], a);
            acc[q] = a;
          }
          const float s01 = acc[0] + acc[1], s23 = acc[2] + acc[3];
          const float s45 = acc[4] + acc[5], s67 = acc[6] + acc[7];
          pn = ((s01 + s23) + (s45 + s67)) * Eb[k];
        }
        // immediate lane-0 pow2 renorm (SALU broadcast)
        const int eb = (__builtin_amdgcn_readfirstlane(__float_as_uint(pn)) >> 23) & 255;
        sacc += eb - 127;
        const float scl = __uint_as_float((unsigned)(254 - eb) << 23);
        pl = pn * scl;
        pbuf[j] = (half1_t)pl;
      } else {
        float q = pl * Eb[k];                // q = beta * E
        const int eb = (__builtin_amdgcn_readfirstlane(__float_as_uint(q)) >> 23) & 255;
        sacc += eb - 127;
        const float scl = __uint_as_float((unsigned)(254 - eb) << 23);
        const float qs = q * scl;
        pbuf[j] = (half1_t)qs;
        const uint4* sh = reinterpret_cast<const uint4*>(pbuf);
        float acc[8];
#pragma unroll
        for (int q2 = 0; q2 < 8; ++q2) {
          const uint4 vv = sh[q2];
          float a;
          a = dot2f(as_h2(vv.x), Wp[4 * q2 + 0], 0.f);
          a = dot2f(as_h2(vv.y), Wp[4 * q2 + 1], a);
          a = dot2f(as_h2(vv.z), Wp[4 * q2 + 2], a);
          a = dot2f(as_h2(vv.w), Wp[4 * q2 + 3], a);
          acc[q2] = a;
        }
        const float s01 = acc[0] + acc[1], s23 = acc[2] + acc[3];
        const float s45 = acc[4] + acc[5], s67 = acc[6] + acc[7];
        pl = (s01 + s23) + (s45 + s67);
      }
    }

    if (more) {
#pragma unroll
      for (int k = 0; k < 8; ++k) xb[k] = xn[k];
    }
  }

  // ---- write results ----
  float* meta = wsf + 32768 + (size_t)b * 8;
  if (dir == 0) {
    wsf[(size_t)b * kC + j] = pl;
    if (j == 0) {
      meta[0] = (float)sacc;
      meta[2] = pe;
    }
  } else {
    wsf[16384 + (size_t)b * kC + j] = pl;
    if (j == 0) {
      meta[4] = (float)sacc;
      meta[6] = pe;
    }
  }
}

// combine: Z = sum_j u[j]*v[j] (with accumulated scales), out = logZ - pathE
__global__ __launch_bounds__(64, 1) void crf_combine(
    const float* __restrict__ wsf, float* __restrict__ out)
{
  const int b = blockIdx.x;
  const int j = threadIdx.x & 63;

  const float u = wsf[(size_t)b * kC + j];
  const float v = wsf[16384 + (size_t)b * kC + j];
  float p = u * v;
#pragma unroll
  for (int off = 32; off >= 1; off >>= 1) p += __shfl_xor(p, off, 64);

  if (j == 0) {
    const float* meta = wsf + 32768 + (size_t)b * 8;
    const float logz = (meta[0] + meta[4]) * 0.69314718055994531f + __logf(p);
    out[b] = logz - (meta[2] + meta[6]);
  }
}

}  // namespace

extern "C" void kernel_launch(void* const* d_in, const int* in_sizes, int n_in,
                              void* d_out, int out_size, void* d_ws, size_t ws_size,
                              hipStream_t stream) {
  const float* x  = (const float*)d_in[0];
  const float* U  = (const float*)d_in[1];
  const float* bs = (const float*)d_in[2];
  const float* be = (const float*)d_in[3];
  const int*   y  = (const int*)d_in[4];
  float* out = (float*)d_out;
  float* wsf = (float*)d_ws;

  crf_half<<<2 * kB, 64, 0, stream>>>(x, U, bs, be, y, wsf);
  crf_combine<<<kB, 64, 0, stream>>>(wsf, out);
}

// Round 10
// 53.554 us; speedup vs baseline: 4.3692x; 2.5766x over previous
//
#include <hip/hip_runtime.h>

namespace {

constexpr int kB = 256;
constexpr int kT = 1024;
constexpr int kC = 64;
constexpr int kS = 20;       // segments per chain
constexpr int kL = 8;        // burn-in steps (Birkhoff contraction ~0.2/step)
constexpr int kNT = kT - 1;  // 1023 transitions

typedef _Float16 half1_t;
typedef _Float16 half2_t __attribute__((ext_vector_type(2)));

#if __has_builtin(__builtin_amdgcn_fdot2)
#define HAVE_FDOT2 1
#else
#define HAVE_FDOT2 0
#endif

__device__ __forceinline__ float dot2f(half2_t a, half2_t b, float c) {
#if HAVE_FDOT2
  return __builtin_amdgcn_fdot2(a, b, c, false);
#else
  return c + (float)a.x * (float)b.x + (float)a.y * (float)b.y;
#endif
}

__device__ __forceinline__ half2_t as_h2(unsigned int u) {
  return __builtin_bit_cast(half2_t, u);
}

__device__ __forceinline__ float wave_sum(float v) {
#pragma unroll
  for (int off = 32; off >= 1; off >>= 1) v += __shfl_xor(v, off, 64);
  return v;
}

// workspace float layout:
//   [0    .. kS*256)   val[ss][b] : per-segment partial log2 sums
//   [8192 .. 8448)     pe[b]      : gold-path energy

// kS*256 blocks x 1 wave. Block (ss,b): segment ss of chain b.
// lane = class. Linear-domain forward recursion, f16 state in LDS, f16 W in
// regs, immediate lane-0 pow2 renorm via readfirstlane (SALU; no shuffles in
// the hot loop — round-8 lesson). Segments ss>0 start from the uniform
// vector and burn in kL steps (Birkhoff contraction ~0.2/step, E-diag
// cancels in cross-ratios); partial sums of log2 growth telescope exactly.
__global__ __launch_bounds__(64, 1) void crf_seg(
    const float* __restrict__ x,    // [B,T,C]
    const float* __restrict__ U,    // [C,C]
    const float* __restrict__ bs,   // [C]
    const float* __restrict__ be,   // [C]
    const int*   __restrict__ y,    // [B,T]
    float*       __restrict__ wsf)
{
  const int blk = blockIdx.x;
  const int ss  = blk >> 8;      // segment id
  const int b   = blk & 255;
  const int j   = threadIdx.x & 63;

  __shared__ __align__(16) half1_t pbuf[kC];

  const float* xbase = x + (size_t)b * kT * kC;
  const float* xcol  = xbase + j;

  // ---- gold-path energy prepass (segment-0 blocks only; t-parallel) ----
  if (ss == 0) {
    const int* yrow = y + (size_t)b * kT;
    float pe = 0.f;
    const int t0 = j * 16;
    int yv[17];
#pragma unroll
    for (int k = 0; k < 16; ++k) yv[k + 1] = yrow[t0 + k];
    yv[0] = (j > 0) ? yrow[t0 - 1] : 0;
#pragma unroll
    for (int k = 0; k < 16; ++k) {
      const int t = t0 + k;
      pe += xbase[(size_t)t * kC + yv[k + 1]];          // emission
      if (t >= 1) pe += U[yv[k] * kC + yv[k + 1]];      // transition
    }
    if (j == 0)  pe += bs[yv[1]];    // boundary on y[0]
    if (j == 63) pe += be[yv[16]];   // boundary on y[T-1]
    pe = wave_sum(pe);
    if (j == 0) wsf[8192 + b] = pe;
  }

  // ---- W column for this lane, f16 pairs: Wp[w] = (W[2w][j], W[2w+1][j]) ----
  half2_t Wp[32];
#pragma unroll
  for (int w = 0; w < 32; ++w) {
    half2_t hw;
    hw.x = (half1_t)__expf(U[(2 * w + 0) * kC + j]);
    hw.y = (half1_t)__expf(U[(2 * w + 1) * kC + j]);
    Wp[w] = hw;
  }
  const float bej = be[j];

  // transition range this segment is accountable for: [t_lo, t_hi]
  const int t_lo    = (kNT * ss) / kS + 1;
  const int t_hi    = (kNT * (ss + 1)) / kS;
  const int t_first = (ss == 0) ? 1 : (t_lo - kL);   // incl. burn-in
  const int nburn   = (ss == 0) ? 0 : kL;
  const int ntot    = t_hi - t_first + 1;

  int   sacc = 0;
  float pl;
  if (ss == 0) {
    // exact alpha_0 = exp(x_0 + b_start), renormalized
    const float pn = __expf(xcol[0] + bs[j]);
    const int eb = (__builtin_amdgcn_readfirstlane(__float_as_uint(pn)) >> 23) & 255;
    sacc = eb - 127;
    pl = pn * __uint_as_float((unsigned)(254 - eb) << 23);
    pbuf[j] = (half1_t)pl;
  } else {
    pl = 1.f;                      // uniform start (direction converges)
    pbuf[j] = (half1_t)1.f;
  }
  float ref = 0.f;                 // log2 reference at accountability start

  // preload group 0
  float xb[8];
#pragma unroll
  for (int k = 0; k < 8; ++k) {
    int t = t_first + k; t = (t > kNT) ? kNT : t;
    xb[k] = xcol[t * kC];
  }

  for (int base = 0; base < ntot; base += 8) {
    float xn[8];
    const bool more = (base + 8 < ntot);
    if (more) {
#pragma unroll
      for (int k = 0; k < 8; ++k) {
        int t = t_first + base + 8 + k; t = (t > kNT) ? kNT : t;
        xn[k] = xcol[t * kC];
      }
    }

    // E for this group — off the p critical path
    float Eb[8];
#pragma unroll
    for (int k = 0; k < 8; ++k) {
      float xe = xb[k];
      if (t_first + base + k == kNT) xe += bej;   // t == T-1 boundary
      Eb[k] = __expf(xe);
    }

#pragma unroll
    for (int k = 0; k < 8; ++k) {
      if (base + k < ntot) {
        // one recursion step: p <- (p W) * E, f16 LDS broadcast
        const uint4* sh = reinterpret_cast<const uint4*>(pbuf);
        float acc[8];
#pragma unroll
        for (int q = 0; q < 8; ++q) {
          const uint4 vv = sh[q];
          float a;
          a = dot2f(as_h2(vv.x), Wp[4 * q + 0], 0.f);
          a = dot2f(as_h2(vv.y), Wp[4 * q + 1], a);
          a = dot2f(as_h2(vv.z), Wp[4 * q + 2], a);
          a = dot2f(as_h2(vv.w), Wp[4 * q + 3], a);
          acc[q] = a;
        }
        const float s01 = acc[0] + acc[1], s23 = acc[2] + acc[3];
        const float s45 = acc[4] + acc[5], s67 = acc[6] + acc[7];
        const float pn = ((s01 + s23) + (s45 + s67)) * Eb[k];

        // immediate lane-0 pow2 renorm (SALU broadcast; round-9 proven)
        const int eb = (__builtin_amdgcn_readfirstlane(__float_as_uint(pn)) >> 23) & 255;
        sacc += eb - 127;
        pl = pn * __uint_as_float((unsigned)(254 - eb) << 23);
        pbuf[j] = (half1_t)pl;

        // end of burn-in: snapshot log2 |p|_1 (butterfly; off hot path)
        if (base + k + 1 == nburn) {
          const float ps = wave_sum(pl);
          ref = __log2f(ps) + (float)sacc;
        }
      }
    }

    if (more) {
#pragma unroll
      for (int k = 0; k < 8; ++k) xb[k] = xn[k];
    }
  }

  // ---- partial: log2 |alpha_{t_hi}| - log2 |alpha_{t_lo-1}| ----
  const float ps  = wave_sum(pl);
  const float val = (__log2f(ps) + (float)sacc) - ref;
  if (j == 0) wsf[ss * 256 + b] = val;
}

// out[b] = ln2 * sum_ss val[ss][b] - pe[b]
__global__ __launch_bounds__(64, 1) void crf_combine(
    const float* __restrict__ wsf, float* __restrict__ out)
{
  const int b = blockIdx.x;
  const int j = threadIdx.x & 63;

  float v = (j < kS) ? wsf[j * 256 + b] : 0.f;
  v = wave_sum(v);

  if (j == 0) {
    out[b] = 0.69314718055994531f * v - wsf[8192 + b];
  }
}

}  // namespace

extern "C" void kernel_launch(void* const* d_in, const int* in_sizes, int n_in,
                              void* d_out, int out_size, void* d_ws, size_t ws_size,
                              hipStream_t stream) {
  const float* x  = (const float*)d_in[0];
  const float* U  = (const float*)d_in[1];
  const float* bs = (const float*)d_in[2];
  const float* be = (const float*)d_in[3];
  const int*   y  = (const int*)d_in[4];
  float* out = (float*)d_out;
  float* wsf = (float*)d_ws;

  crf_seg<<<kS * kB, 64, 0, stream>>>(x, U, bs, be, y, wsf);
  crf_combine<<<kB, 64, 0, stream>>>(wsf, out);
}